// Round 1
// baseline (1169.935 us; speedup 1.0000x reference)
//
#include <hip/hip_runtime.h>

#define CDIM 128
#define NGRAPH 256

// ---------- CSR build ----------
__global__ void k_hist(const int* __restrict__ dst, int* __restrict__ counts, int E) {
  int e = blockIdx.x * blockDim.x + threadIdx.x;
  if (e < E) atomicAdd(&counts[dst[e]], 1);
}

__global__ __launch_bounds__(1024) void k_scan(const int* __restrict__ counts,
    int* __restrict__ rowptr, int* __restrict__ cursor, float* __restrict__ dinv, int N) {
  __shared__ int sh[1024];
  int tid = threadIdx.x;
  int chk = (N + 1023) >> 10;
  int base = tid * chk;
  int s = 0;
  for (int i = 0; i < chk; i++) { int idx = base + i; if (idx < N) s += counts[idx]; }
  sh[tid] = s;
  __syncthreads();
  for (int ofs = 1; ofs < 1024; ofs <<= 1) {
    int v = (tid >= ofs) ? sh[tid - ofs] : 0;
    __syncthreads();
    sh[tid] += v;
    __syncthreads();
  }
  int run = (tid == 0) ? 0 : sh[tid - 1];
  for (int i = 0; i < chk; i++) {
    int idx = base + i;
    if (idx < N) {
      int c = counts[idx];
      rowptr[idx] = run; cursor[idx] = run;
      dinv[idx] = rsqrtf((float)c + 1.0f);  // deg = in-degree + self loop
      run += c;
    }
  }
  if (tid == 1023) rowptr[N] = run;
}

__global__ void k_fill(const int* __restrict__ src, const int* __restrict__ dst,
                       int* __restrict__ cursor, int* __restrict__ col, int E) {
  int e = blockIdx.x * blockDim.x + threadIdx.x;
  if (e < E) {
    int d = dst[e];
    int p = atomicAdd(&cursor[d], 1);
    col[p] = src[e];
  }
}

// ---------- GEMM: [M x 128] @ [128 x 128], fp32, 128-row tile, 8x8 microtile ----------
__global__ __launch_bounds__(256) void k_gemm(const float* __restrict__ A,
    const float* __restrict__ W, float* __restrict__ Co, int M) {
  __shared__ float At[32][CDIM + 4];  // transposed A chunk: At[k][row]
  __shared__ float Ws[32][CDIM + 4];  // Ws[k][col]
  int tid = threadIdx.x;
  int tx = tid & 15, ty = tid >> 4;
  int row0 = blockIdx.x * 128;
  float acc[8][8];
#pragma unroll
  for (int i = 0; i < 8; i++)
#pragma unroll
    for (int j = 0; j < 8; j++) acc[i][j] = 0.f;

  for (int kc = 0; kc < 4; kc++) {
    int kb = kc * 32;
#pragma unroll
    for (int i = 0; i < 4; i++) {
      int f = tid + i * 256;          // 0..1023 float4 slots
      int r = f >> 3;                 // A row in tile (0..127)
      int kq = (f & 7) << 2;          // k quad
      int gr = row0 + r; if (gr >= M) gr = M - 1;
      float4 av = *(const float4*)&A[(size_t)gr * CDIM + kb + kq];
      At[kq + 0][r] = av.x; At[kq + 1][r] = av.y; At[kq + 2][r] = av.z; At[kq + 3][r] = av.w;
      int wr = f >> 5;                // W row (k) 0..31
      int cq = (f & 31) << 2;         // col quad
      *(float4*)&Ws[wr][cq] = *(const float4*)&W[(size_t)(kb + wr) * CDIM + cq];
    }
    __syncthreads();
#pragma unroll
    for (int kk = 0; kk < 32; kk++) {
      float a[8], wv[8];
      *(float4*)&a[0] = *(const float4*)&At[kk][ty * 8];
      *(float4*)&a[4] = *(const float4*)&At[kk][ty * 8 + 4];
      *(float4*)&wv[0] = *(const float4*)&Ws[kk][tx * 4];        // cols tx*4..+3
      *(float4*)&wv[4] = *(const float4*)&Ws[kk][tx * 4 + 64];   // cols tx*4+64..+67
#pragma unroll
      for (int i = 0; i < 8; i++)
#pragma unroll
        for (int j = 0; j < 8; j++) acc[i][j] = fmaf(a[i], wv[j], acc[i][j]);
    }
    __syncthreads();
  }
#pragma unroll
  for (int i = 0; i < 8; i++) {
    int r = row0 + ty * 8 + i;
    if (r < M) {
      float4 v0 = make_float4(acc[i][0], acc[i][1], acc[i][2], acc[i][3]);
      float4 v1 = make_float4(acc[i][4], acc[i][5], acc[i][6], acc[i][7]);
      *(float4*)&Co[(size_t)r * CDIM + tx * 4] = v0;
      *(float4*)&Co[(size_t)r * CDIM + tx * 4 + 64] = v1;
    }
  }
}

// ---------- per-node gather aggregation + bias + relu (one wave per node) ----------
__global__ __launch_bounds__(256) void k_agg(const float* __restrict__ t,
    const int* __restrict__ rowptr, const int* __restrict__ col,
    const float* __restrict__ dinv, const float* __restrict__ bias,
    float* __restrict__ out, int N) {
  int wave = threadIdx.x >> 6;
  int lane = threadIdx.x & 63;
  int node = blockIdx.x * 4 + wave;
  if (node >= N) return;
  int c0 = lane * 2;
  float di = dinv[node];
  float2 sv = ((const float2*)&t[(size_t)node * CDIM])[lane];
  float sw = di * di;                       // self-loop norm
  float ax = sv.x * sw, ay = sv.y * sw;
  int beg = rowptr[node], end = rowptr[node + 1];
  for (int j = beg; j < end; j++) {
    int s = col[j];
    float wgt = dinv[s] * di;
    float2 v = ((const float2*)&t[(size_t)s * CDIM])[lane];
    ax = fmaf(v.x, wgt, ax);
    ay = fmaf(v.y, wgt, ay);
  }
  ax += bias[c0]; ay += bias[c0 + 1];
  ax = fmaxf(ax, 0.f); ay = fmaxf(ay, 0.f);
  float2 o; o.x = ax; o.y = ay;
  ((float2*)&out[(size_t)node * CDIM])[lane] = o;
}

// ---------- global mean pool (batch is sorted) ----------
__global__ __launch_bounds__(128) void k_pool(const float* __restrict__ h,
    const int* __restrict__ batch, float* __restrict__ g, int N) {
  int b = blockIdx.x;
  int lo = 0, hi = N;
  while (lo < hi) { int mid = (lo + hi) >> 1; if (batch[mid] < b) lo = mid + 1; else hi = mid; }
  int s = lo;
  lo = 0; hi = N;
  int key = b + 1;
  while (lo < hi) { int mid = (lo + hi) >> 1; if (batch[mid] < key) lo = mid + 1; else hi = mid; }
  int e = lo;
  int c = threadIdx.x;
  float acc = 0.f;
  for (int i = s; i < e; i++) acc += h[(size_t)i * CDIM + c];
  g[b * CDIM + c] = acc / fmaxf((float)(e - s), 1.f);
}

// ---------- MLP head ----------
__global__ __launch_bounds__(512) void k_mlp1(const float* __restrict__ g,
    const float* __restrict__ W, const float* __restrict__ b, float* __restrict__ o) {
  __shared__ float gs[CDIM];
  int bi = blockIdx.x, tid = threadIdx.x;
  if (tid < CDIM) gs[tid] = g[bi * CDIM + tid];
  __syncthreads();
  if (tid < 500) {
    float acc = b[tid];
#pragma unroll 4
    for (int k = 0; k < CDIM; k++) acc = fmaf(gs[k], W[k * 500 + tid], acc);
    o[bi * 500 + tid] = fmaxf(acc, 0.f);
  }
}

__global__ __launch_bounds__(128) void k_mlp2(const float* __restrict__ a,
    const float* __restrict__ W, const float* __restrict__ b, float* __restrict__ o) {
  __shared__ float as[500];
  int bi = blockIdx.x, tid = threadIdx.x;
  for (int k = tid; k < 500; k += 128) as[k] = a[bi * 500 + k];
  __syncthreads();
  if (tid < 100) {
    float acc = b[tid];
    for (int k = 0; k < 500; k++) acc = fmaf(as[k], W[k * 100 + tid], acc);
    o[bi * 100 + tid] = fmaxf(acc, 0.f);
  }
}

__global__ __launch_bounds__(64) void k_mlp3(const float* __restrict__ a,
    const float* __restrict__ w, const float* __restrict__ b, float* __restrict__ o) {
  int bi = blockIdx.x, lane = threadIdx.x;
  float v = a[bi * 100 + lane] * w[lane];
  if (lane + 64 < 100) v = fmaf(a[bi * 100 + lane + 64], w[lane + 64], v);
#pragma unroll
  for (int ofs = 32; ofs > 0; ofs >>= 1) v += __shfl_down(v, ofs, 64);
  if (lane == 0) o[bi] = v + b[0];
}

static inline size_t align_up(size_t v) { return (v + 255) & ~(size_t)255; }

extern "C" void kernel_launch(void* const* d_in, const int* in_sizes, int n_in,
                              void* d_out, int out_size, void* d_ws, size_t ws_size,
                              hipStream_t stream) {
  const float* x   = (const float*)d_in[0];
  const int*   ei  = (const int*)d_in[1];
  const int*   bat = (const int*)d_in[2];
  const float* W1  = (const float*)d_in[3];
  const float* b1  = (const float*)d_in[4];
  const float* W2  = (const float*)d_in[5];
  const float* b2  = (const float*)d_in[6];
  const float* Wm1 = (const float*)d_in[7];
  const float* bm1 = (const float*)d_in[8];
  const float* Wm2 = (const float*)d_in[9];
  const float* bm2 = (const float*)d_in[10];
  const float* Wm3 = (const float*)d_in[11];
  const float* bm3 = (const float*)d_in[12];
  float* out = (float*)d_out;

  const int E = in_sizes[1] / 2;
  const int N = in_sizes[2];
  const int* src = ei;
  const int* dst = ei + E;

  char* p = (char*)d_ws;
  float* t    = (float*)p; p += align_up((size_t)N * CDIM * 4);
  float* h    = (float*)p; p += align_up((size_t)N * CDIM * 4);
  int* counts = (int*)p;   p += align_up((size_t)N * 4);
  int* rowptr = (int*)p;   p += align_up((size_t)(N + 1) * 4);
  int* cursor = (int*)p;   p += align_up((size_t)N * 4);
  int* colx   = (int*)p;   p += align_up((size_t)E * 4);
  float* dinv = (float*)p; p += align_up((size_t)N * 4);
  float* gb   = (float*)p; p += align_up((size_t)NGRAPH * CDIM * 4);
  float* m1   = (float*)p; p += align_up((size_t)NGRAPH * 500 * 4);
  float* m2   = (float*)p; p += align_up((size_t)NGRAPH * 100 * 4);
  (void)ws_size; (void)n_in; (void)out_size;

  hipMemsetAsync(counts, 0, (size_t)N * 4, stream);
  k_hist<<<(E + 255) / 256, 256, 0, stream>>>(dst, counts, E);
  k_scan<<<1, 1024, 0, stream>>>(counts, rowptr, cursor, dinv, N);
  k_fill<<<(E + 255) / 256, 256, 0, stream>>>(src, dst, cursor, colx, E);

  k_gemm<<<(N + 127) / 128, 256, 0, stream>>>(x, W1, t, N);
  k_agg<<<(N + 3) / 4, 256, 0, stream>>>(t, rowptr, colx, dinv, b1, h, N);
  k_gemm<<<(N + 127) / 128, 256, 0, stream>>>(h, W2, t, N);
  k_agg<<<(N + 3) / 4, 256, 0, stream>>>(t, rowptr, colx, dinv, b2, h, N);

  k_pool<<<NGRAPH, 128, 0, stream>>>(h, bat, gb, N);
  k_mlp1<<<NGRAPH, 512, 0, stream>>>(gb, Wm1, bm1, m1);
  k_mlp2<<<NGRAPH, 128, 0, stream>>>(m1, Wm2, bm2, m2);
  k_mlp3<<<NGRAPH, 64, 0, stream>>>(m2, Wm3, bm3, out);
}

// Round 2
// 883.966 us; speedup vs baseline: 1.3235x; 1.3235x over previous
//
#include <hip/hip_runtime.h>

#define CDIM 128
#define NGRAPH 256

// ---------- CSR build ----------
__global__ void k_hist(const int* __restrict__ dst, int* __restrict__ counts, int E) {
  int e = blockIdx.x * blockDim.x + threadIdx.x;
  if (e < E) atomicAdd(&counts[dst[e]], 1);
}

// Phase A: per-block (4096-elem tile) partial sums, int4-coalesced.
__global__ __launch_bounds__(1024) void k_bsum(const int* __restrict__ counts,
    int* __restrict__ bsums, int N) {
  __shared__ int wsum[16];
  int tid = threadIdx.x;
  int base = blockIdx.x * 4096 + tid * 4;
  int4 c = make_int4(0, 0, 0, 0);
  if (base + 3 < N) c = *(const int4*)&counts[base];
  else {
    if (base + 0 < N) c.x = counts[base + 0];
    if (base + 1 < N) c.y = counts[base + 1];
    if (base + 2 < N) c.z = counts[base + 2];
  }
  int s = c.x + c.y + c.z + c.w;
#pragma unroll
  for (int ofs = 32; ofs > 0; ofs >>= 1) s += __shfl_down(s, ofs, 64);
  if ((tid & 63) == 0) wsum[tid >> 6] = s;
  __syncthreads();
  if (tid == 0) {
    int t = 0;
#pragma unroll
    for (int i = 0; i < 16; i++) t += wsum[i];
    bsums[blockIdx.x] = t;
  }
}

// Phase B: exclusive scan of block sums (G <= 1024), one block.
__global__ __launch_bounds__(1024) void k_boff(const int* __restrict__ bsums,
    int* __restrict__ boffs, int G) {
  __shared__ int sh[1024];
  int tid = threadIdx.x;
  int v = (tid < G) ? bsums[tid] : 0;
  sh[tid] = v;
  __syncthreads();
  for (int ofs = 1; ofs < 1024; ofs <<= 1) {
    int u = (tid >= ofs) ? sh[tid - ofs] : 0;
    __syncthreads();
    sh[tid] += u;
    __syncthreads();
  }
  if (tid < G) boffs[tid] = sh[tid] - v;   // exclusive
  if (tid == G) boffs[G] = (G > 0) ? sh[G - 1] : 0;  // total (tid==G < 1024 since G<1024)
  if (tid == 0 && G == 1024) { /* unreachable for N=100k */ }
}

// Phase C: per-tile exclusive scan + block offset; writes rowptr/cursor/dinv.
__global__ __launch_bounds__(1024) void k_scan2(const int* __restrict__ counts,
    const int* __restrict__ boffs, int* __restrict__ rowptr, int* __restrict__ cursor,
    float* __restrict__ dinv, int N) {
  __shared__ int wsum[16];
  int tid = threadIdx.x;
  int lane = tid & 63, wave = tid >> 6;
  int base = blockIdx.x * 4096 + tid * 4;
  int4 c = make_int4(0, 0, 0, 0);
  if (base + 3 < N) c = *(const int4*)&counts[base];
  else {
    if (base + 0 < N) c.x = counts[base + 0];
    if (base + 1 < N) c.y = counts[base + 1];
    if (base + 2 < N) c.z = counts[base + 2];
  }
  int tsum = c.x + c.y + c.z + c.w;
  int v = tsum;
#pragma unroll
  for (int ofs = 1; ofs < 64; ofs <<= 1) {
    int u = __shfl_up(v, ofs, 64);
    if (lane >= ofs) v += u;
  }
  if (lane == 63) wsum[wave] = v;
  __syncthreads();
  if (wave == 0) {
    int w = (lane < 16) ? wsum[lane] : 0;
#pragma unroll
    for (int ofs = 1; ofs < 16; ofs <<= 1) {
      int u = __shfl_up(w, ofs, 64);
      if (lane >= ofs) w += u;
    }
    if (lane < 16) wsum[lane] = w;
  }
  __syncthreads();
  int waveoff = (wave == 0) ? 0 : wsum[wave - 1];
  int excl = boffs[blockIdx.x] + waveoff + (v - tsum);
  int r[4]; r[0] = excl; r[1] = r[0] + c.x; r[2] = r[1] + c.y; r[3] = r[2] + c.z;
  int cc[4] = {c.x, c.y, c.z, c.w};
#pragma unroll
  for (int k = 0; k < 4; k++) {
    int idx = base + k;
    if (idx < N) {
      rowptr[idx] = r[k];
      cursor[idx] = r[k];
      dinv[idx] = rsqrtf((float)cc[k] + 1.0f);  // deg = in-degree + self loop
    }
  }
  if (blockIdx.x == 0 && tid == 0) rowptr[N] = boffs[gridDim.x];
}

__global__ void k_fill(const int* __restrict__ src, const int* __restrict__ dst,
                       int* __restrict__ cursor, int* __restrict__ col, int E) {
  int e = blockIdx.x * blockDim.x + threadIdx.x;
  if (e < E) {
    int d = dst[e];
    int p = atomicAdd(&cursor[d], 1);
    col[p] = src[e];
  }
}

// ---------- GEMM: [M x 128] @ [128 x 128], fp32, 128-row tile, 8x8 microtile ----------
__global__ __launch_bounds__(256) void k_gemm(const float* __restrict__ A,
    const float* __restrict__ W, float* __restrict__ Co, int M) {
  __shared__ float At[32][CDIM + 4];  // transposed A chunk: At[k][row]
  __shared__ float Ws[32][CDIM + 4];  // Ws[k][col]
  int tid = threadIdx.x;
  int tx = tid & 15, ty = tid >> 4;
  int row0 = blockIdx.x * 128;
  float acc[8][8];
#pragma unroll
  for (int i = 0; i < 8; i++)
#pragma unroll
    for (int j = 0; j < 8; j++) acc[i][j] = 0.f;

  for (int kc = 0; kc < 4; kc++) {
    int kb = kc * 32;
#pragma unroll
    for (int i = 0; i < 4; i++) {
      int f = tid + i * 256;          // 0..1023 float4 slots
      int r = f >> 3;                 // A row in tile (0..127)
      int kq = (f & 7) << 2;          // k quad
      int gr = row0 + r; if (gr >= M) gr = M - 1;
      float4 av = *(const float4*)&A[(size_t)gr * CDIM + kb + kq];
      At[kq + 0][r] = av.x; At[kq + 1][r] = av.y; At[kq + 2][r] = av.z; At[kq + 3][r] = av.w;
      int wr = f >> 5;                // W row (k) 0..31
      int cq = (f & 31) << 2;         // col quad
      *(float4*)&Ws[wr][cq] = *(const float4*)&W[(size_t)(kb + wr) * CDIM + cq];
    }
    __syncthreads();
#pragma unroll
    for (int kk = 0; kk < 32; kk++) {
      float a[8], wv[8];
      *(float4*)&a[0] = *(const float4*)&At[kk][ty * 8];
      *(float4*)&a[4] = *(const float4*)&At[kk][ty * 8 + 4];
      *(float4*)&wv[0] = *(const float4*)&Ws[kk][tx * 4];        // cols tx*4..+3
      *(float4*)&wv[4] = *(const float4*)&Ws[kk][tx * 4 + 64];   // cols tx*4+64..+67
#pragma unroll
      for (int i = 0; i < 8; i++)
#pragma unroll
        for (int j = 0; j < 8; j++) acc[i][j] = fmaf(a[i], wv[j], acc[i][j]);
    }
    __syncthreads();
  }
#pragma unroll
  for (int i = 0; i < 8; i++) {
    int r = row0 + ty * 8 + i;
    if (r < M) {
      float4 v0 = make_float4(acc[i][0], acc[i][1], acc[i][2], acc[i][3]);
      float4 v1 = make_float4(acc[i][4], acc[i][5], acc[i][6], acc[i][7]);
      *(float4*)&Co[(size_t)r * CDIM + tx * 4] = v0;
      *(float4*)&Co[(size_t)r * CDIM + tx * 4 + 64] = v1;
    }
  }
}

// ---------- per-node gather aggregation + bias + relu (one wave per node) ----------
__global__ __launch_bounds__(256) void k_agg(const float* __restrict__ t,
    const int* __restrict__ rowptr, const int* __restrict__ col,
    const float* __restrict__ dinv, const float* __restrict__ bias,
    float* __restrict__ out, int N) {
  int wave = threadIdx.x >> 6;
  int lane = threadIdx.x & 63;
  int node = blockIdx.x * 4 + wave;
  if (node >= N) return;
  int c0 = lane * 2;
  float di = dinv[node];
  float2 sv = ((const float2*)&t[(size_t)node * CDIM])[lane];
  float sw = di * di;                       // self-loop norm
  float ax = sv.x * sw, ay = sv.y * sw;
  int beg = rowptr[node], end = rowptr[node + 1];
  for (int j = beg; j < end; j++) {
    int s = col[j];
    float wgt = dinv[s] * di;
    float2 v = ((const float2*)&t[(size_t)s * CDIM])[lane];
    ax = fmaf(v.x, wgt, ax);
    ay = fmaf(v.y, wgt, ay);
  }
  ax += bias[c0]; ay += bias[c0 + 1];
  ax = fmaxf(ax, 0.f); ay = fmaxf(ay, 0.f);
  float2 o; o.x = ax; o.y = ay;
  ((float2*)&out[(size_t)node * CDIM])[lane] = o;
}

// ---------- global mean pool (batch is sorted) ----------
__global__ __launch_bounds__(128) void k_pool(const float* __restrict__ h,
    const int* __restrict__ batch, float* __restrict__ g, int N) {
  int b = blockIdx.x;
  int lo = 0, hi = N;
  while (lo < hi) { int mid = (lo + hi) >> 1; if (batch[mid] < b) lo = mid + 1; else hi = mid; }
  int s = lo;
  lo = 0; hi = N;
  int key = b + 1;
  while (lo < hi) { int mid = (lo + hi) >> 1; if (batch[mid] < key) lo = mid + 1; else hi = mid; }
  int e = lo;
  int c = threadIdx.x;
  float acc = 0.f;
  for (int i = s; i < e; i++) acc += h[(size_t)i * CDIM + c];
  g[b * CDIM + c] = acc / fmaxf((float)(e - s), 1.f);
}

// ---------- MLP head ----------
__global__ __launch_bounds__(512) void k_mlp1(const float* __restrict__ g,
    const float* __restrict__ W, const float* __restrict__ b, float* __restrict__ o) {
  __shared__ float gs[CDIM];
  int bi = blockIdx.x, tid = threadIdx.x;
  if (tid < CDIM) gs[tid] = g[bi * CDIM + tid];
  __syncthreads();
  if (tid < 500) {
    float acc = b[tid];
#pragma unroll 4
    for (int k = 0; k < CDIM; k++) acc = fmaf(gs[k], W[k * 500 + tid], acc);
    o[bi * 500 + tid] = fmaxf(acc, 0.f);
  }
}

__global__ __launch_bounds__(128) void k_mlp2(const float* __restrict__ a,
    const float* __restrict__ W, const float* __restrict__ b, float* __restrict__ o) {
  __shared__ float as[500];
  int bi = blockIdx.x, tid = threadIdx.x;
  for (int k = tid; k < 500; k += 128) as[k] = a[bi * 500 + k];
  __syncthreads();
  if (tid < 100) {
    float acc = b[tid];
    for (int k = 0; k < 500; k++) acc = fmaf(as[k], W[k * 100 + tid], acc);
    o[bi * 100 + tid] = fmaxf(acc, 0.f);
  }
}

__global__ __launch_bounds__(64) void k_mlp3(const float* __restrict__ a,
    const float* __restrict__ w, const float* __restrict__ b, float* __restrict__ o) {
  int bi = blockIdx.x, lane = threadIdx.x;
  float v = a[bi * 100 + lane] * w[lane];
  if (lane + 64 < 100) v = fmaf(a[bi * 100 + lane + 64], w[lane + 64], v);
#pragma unroll
  for (int ofs = 32; ofs > 0; ofs >>= 1) v += __shfl_down(v, ofs, 64);
  if (lane == 0) o[bi] = v + b[0];
}

static inline size_t align_up(size_t v) { return (v + 255) & ~(size_t)255; }

extern "C" void kernel_launch(void* const* d_in, const int* in_sizes, int n_in,
                              void* d_out, int out_size, void* d_ws, size_t ws_size,
                              hipStream_t stream) {
  const float* x   = (const float*)d_in[0];
  const int*   ei  = (const int*)d_in[1];
  const int*   bat = (const int*)d_in[2];
  const float* W1  = (const float*)d_in[3];
  const float* b1  = (const float*)d_in[4];
  const float* W2  = (const float*)d_in[5];
  const float* b2  = (const float*)d_in[6];
  const float* Wm1 = (const float*)d_in[7];
  const float* bm1 = (const float*)d_in[8];
  const float* Wm2 = (const float*)d_in[9];
  const float* bm2 = (const float*)d_in[10];
  const float* Wm3 = (const float*)d_in[11];
  const float* bm3 = (const float*)d_in[12];
  float* out = (float*)d_out;

  const int E = in_sizes[1] / 2;
  const int N = in_sizes[2];
  const int* src = ei;
  const int* dst = ei + E;
  const int G = (N + 4095) / 4096;

  char* p = (char*)d_ws;
  float* t    = (float*)p; p += align_up((size_t)N * CDIM * 4);
  float* h    = (float*)p; p += align_up((size_t)N * CDIM * 4);
  int* counts = (int*)p;   p += align_up((size_t)N * 4);
  int* rowptr = (int*)p;   p += align_up((size_t)(N + 1) * 4);
  int* cursor = (int*)p;   p += align_up((size_t)N * 4);
  int* colx   = (int*)p;   p += align_up((size_t)E * 4);
  float* dinv = (float*)p; p += align_up((size_t)N * 4);
  int* bsums  = (int*)p;   p += align_up((size_t)G * 4);
  int* boffs  = (int*)p;   p += align_up((size_t)(G + 1) * 4);
  float* gb   = (float*)p; p += align_up((size_t)NGRAPH * CDIM * 4);
  float* m1   = (float*)p; p += align_up((size_t)NGRAPH * 500 * 4);
  float* m2   = (float*)p; p += align_up((size_t)NGRAPH * 100 * 4);
  (void)ws_size; (void)n_in; (void)out_size;

  hipMemsetAsync(counts, 0, (size_t)N * 4, stream);
  k_hist<<<(E + 255) / 256, 256, 0, stream>>>(dst, counts, E);
  k_bsum<<<G, 1024, 0, stream>>>(counts, bsums, N);
  k_boff<<<1, 1024, 0, stream>>>(bsums, boffs, G);
  k_scan2<<<G, 1024, 0, stream>>>(counts, boffs, rowptr, cursor, dinv, N);
  k_fill<<<(E + 255) / 256, 256, 0, stream>>>(src, dst, cursor, colx, E);

  k_gemm<<<(N + 127) / 128, 256, 0, stream>>>(x, W1, t, N);
  k_agg<<<(N + 3) / 4, 256, 0, stream>>>(t, rowptr, colx, dinv, b1, h, N);
  k_gemm<<<(N + 127) / 128, 256, 0, stream>>>(h, W2, t, N);
  k_agg<<<(N + 3) / 4, 256, 0, stream>>>(t, rowptr, colx, dinv, b2, h, N);

  k_pool<<<NGRAPH, 128, 0, stream>>>(h, bat, gb, N);
  k_mlp1<<<NGRAPH, 512, 0, stream>>>(gb, Wm1, bm1, m1);
  k_mlp2<<<NGRAPH, 128, 0, stream>>>(m1, Wm2, bm2, m2);
  k_mlp3<<<NGRAPH, 64, 0, stream>>>(m2, Wm3, bm3, out);
}

// Round 3
// 661.846 us; speedup vs baseline: 1.7677x; 1.3356x over previous
//
#include <hip/hip_runtime.h>

#define CDIM 128
#define NGRAPH 256

typedef unsigned short bf16_t;

__device__ __forceinline__ float bflo(unsigned u) { return __uint_as_float(u << 16); }
__device__ __forceinline__ float bfhi(unsigned u) { return __uint_as_float(u & 0xffff0000u); }
__device__ __forceinline__ unsigned short f2bf(float f) {
  unsigned u = __float_as_uint(f);
  u += 0x7fffu + ((u >> 16) & 1u);   // round-to-nearest-even
  return (unsigned short)(u >> 16);
}
__device__ __forceinline__ float bf2f(unsigned short s) {
  return __uint_as_float((unsigned)s << 16);
}

// ---------- CSR build ----------
__global__ void k_hist(const int* __restrict__ dst, int* __restrict__ counts, int E) {
  int e = blockIdx.x * blockDim.x + threadIdx.x;
  if (e < E) atomicAdd(&counts[dst[e]], 1);
}

// Phase A: per-block (4096-elem tile) partial sums, int4-coalesced.
__global__ __launch_bounds__(1024) void k_bsum(const int* __restrict__ counts,
    int* __restrict__ bsums, int N) {
  __shared__ int wsum[16];
  int tid = threadIdx.x;
  int base = blockIdx.x * 4096 + tid * 4;
  int4 c = make_int4(0, 0, 0, 0);
  if (base + 3 < N) c = *(const int4*)&counts[base];
  else {
    if (base + 0 < N) c.x = counts[base + 0];
    if (base + 1 < N) c.y = counts[base + 1];
    if (base + 2 < N) c.z = counts[base + 2];
  }
  int s = c.x + c.y + c.z + c.w;
#pragma unroll
  for (int ofs = 32; ofs > 0; ofs >>= 1) s += __shfl_down(s, ofs, 64);
  if ((tid & 63) == 0) wsum[tid >> 6] = s;
  __syncthreads();
  if (tid == 0) {
    int t = 0;
#pragma unroll
    for (int i = 0; i < 16; i++) t += wsum[i];
    bsums[blockIdx.x] = t;
  }
}

// Phase B: exclusive scan of block sums (G <= 1023), one block.
__global__ __launch_bounds__(1024) void k_boff(const int* __restrict__ bsums,
    int* __restrict__ boffs, int G) {
  __shared__ int sh[1024];
  int tid = threadIdx.x;
  int v = (tid < G) ? bsums[tid] : 0;
  sh[tid] = v;
  __syncthreads();
  for (int ofs = 1; ofs < 1024; ofs <<= 1) {
    int u = (tid >= ofs) ? sh[tid - ofs] : 0;
    __syncthreads();
    sh[tid] += u;
    __syncthreads();
  }
  if (tid < G) boffs[tid] = sh[tid] - v;            // exclusive
  if (tid == G) boffs[G] = (G > 0) ? sh[G - 1] : 0; // total
}

// Phase C: per-tile exclusive scan + block offset; writes rowptr/cursor/dinv.
__global__ __launch_bounds__(1024) void k_scan2(const int* __restrict__ counts,
    const int* __restrict__ boffs, int* __restrict__ rowptr, int* __restrict__ cursor,
    float* __restrict__ dinv, int N) {
  __shared__ int wsum[16];
  int tid = threadIdx.x;
  int lane = tid & 63, wave = tid >> 6;
  int base = blockIdx.x * 4096 + tid * 4;
  int4 c = make_int4(0, 0, 0, 0);
  if (base + 3 < N) c = *(const int4*)&counts[base];
  else {
    if (base + 0 < N) c.x = counts[base + 0];
    if (base + 1 < N) c.y = counts[base + 1];
    if (base + 2 < N) c.z = counts[base + 2];
  }
  int tsum = c.x + c.y + c.z + c.w;
  int v = tsum;
#pragma unroll
  for (int ofs = 1; ofs < 64; ofs <<= 1) {
    int u = __shfl_up(v, ofs, 64);
    if (lane >= ofs) v += u;
  }
  if (lane == 63) wsum[wave] = v;
  __syncthreads();
  if (wave == 0) {
    int w = (lane < 16) ? wsum[lane] : 0;
#pragma unroll
    for (int ofs = 1; ofs < 16; ofs <<= 1) {
      int u = __shfl_up(w, ofs, 64);
      if (lane >= ofs) w += u;
    }
    if (lane < 16) wsum[lane] = w;
  }
  __syncthreads();
  int waveoff = (wave == 0) ? 0 : wsum[wave - 1];
  int excl = boffs[blockIdx.x] + waveoff + (v - tsum);
  int r[4]; r[0] = excl; r[1] = r[0] + c.x; r[2] = r[1] + c.y; r[3] = r[2] + c.z;
  int cc[4] = {c.x, c.y, c.z, c.w};
#pragma unroll
  for (int k = 0; k < 4; k++) {
    int idx = base + k;
    if (idx < N) {
      rowptr[idx] = r[k];
      cursor[idx] = r[k];
      dinv[idx] = rsqrtf((float)cc[k] + 1.0f);  // deg = in-degree + self loop
    }
  }
  if (blockIdx.x == 0 && tid == 0) rowptr[N] = boffs[gridDim.x];
}

__global__ void k_fill(const int* __restrict__ src, const int* __restrict__ dst,
                       int* __restrict__ cursor, int* __restrict__ col, int E) {
  int e = blockIdx.x * blockDim.x + threadIdx.x;
  if (e < E) {
    int d = dst[e];
    int p = atomicAdd(&cursor[d], 1);
    col[p] = src[e];
  }
}

// ---------- GEMM: [M x 128] @ [128 x 128], fp32 math, bf16 output ----------
// BF16IN=0: A is fp32; BF16IN=1: A is bf16.
template <int BF16IN>
__global__ __launch_bounds__(256) void k_gemm(const void* __restrict__ Ap,
    const float* __restrict__ W, bf16_t* __restrict__ Co, int M) {
  __shared__ float At[32][CDIM + 4];  // transposed A chunk: At[k][row]
  __shared__ float Ws[32][CDIM + 4];  // Ws[k][col]
  int tid = threadIdx.x;
  int tx = tid & 15, ty = tid >> 4;
  int row0 = blockIdx.x * 128;
  float acc[8][8];
#pragma unroll
  for (int i = 0; i < 8; i++)
#pragma unroll
    for (int j = 0; j < 8; j++) acc[i][j] = 0.f;

  for (int kc = 0; kc < 4; kc++) {
    int kb = kc * 32;
#pragma unroll
    for (int i = 0; i < 4; i++) {
      int f = tid + i * 256;          // 0..1023 quad slots
      int r = f >> 3;                 // A row in tile (0..127)
      int kq = (f & 7) << 2;          // k quad
      int gr = row0 + r; if (gr >= M) gr = M - 1;
      float4 av;
      if (BF16IN) {
        ushort4 u = *(const ushort4*)((const bf16_t*)Ap + (size_t)gr * CDIM + kb + kq);
        av.x = bf2f(u.x); av.y = bf2f(u.y); av.z = bf2f(u.z); av.w = bf2f(u.w);
      } else {
        av = *(const float4*)((const float*)Ap + (size_t)gr * CDIM + kb + kq);
      }
      At[kq + 0][r] = av.x; At[kq + 1][r] = av.y; At[kq + 2][r] = av.z; At[kq + 3][r] = av.w;
      int wr = f >> 5;                // W row (k) 0..31
      int cq = (f & 31) << 2;         // col quad
      *(float4*)&Ws[wr][cq] = *(const float4*)&W[(size_t)(kb + wr) * CDIM + cq];
    }
    __syncthreads();
#pragma unroll
    for (int kk = 0; kk < 32; kk++) {
      float a[8], wv[8];
      *(float4*)&a[0] = *(const float4*)&At[kk][ty * 8];
      *(float4*)&a[4] = *(const float4*)&At[kk][ty * 8 + 4];
      *(float4*)&wv[0] = *(const float4*)&Ws[kk][tx * 4];
      *(float4*)&wv[4] = *(const float4*)&Ws[kk][tx * 4 + 64];
#pragma unroll
      for (int i = 0; i < 8; i++)
#pragma unroll
        for (int j = 0; j < 8; j++) acc[i][j] = fmaf(a[i], wv[j], acc[i][j]);
    }
    __syncthreads();
  }
#pragma unroll
  for (int i = 0; i < 8; i++) {
    int r = row0 + ty * 8 + i;
    if (r < M) {
      uint2 o0, o1;
      o0.x = ((unsigned)f2bf(acc[i][1]) << 16) | f2bf(acc[i][0]);
      o0.y = ((unsigned)f2bf(acc[i][3]) << 16) | f2bf(acc[i][2]);
      o1.x = ((unsigned)f2bf(acc[i][5]) << 16) | f2bf(acc[i][4]);
      o1.y = ((unsigned)f2bf(acc[i][7]) << 16) | f2bf(acc[i][6]);
      *(uint2*)&Co[(size_t)r * CDIM + tx * 4]      = o0;
      *(uint2*)&Co[(size_t)r * CDIM + tx * 4 + 64] = o1;
    }
  }
}

// ---------- per-node gather aggregation + bias + relu (one wave per node) ----------
// bf16 rows (256 B), one uint (2 channels) per lane. Edge list preloaded into
// registers (1 coalesced load / 64 edges) and broadcast via shfl; gather loop
// unrolled x4 for 4 outstanding row loads.
__global__ __launch_bounds__(256) void k_agg(const bf16_t* __restrict__ t,
    const int* __restrict__ rowptr, const int* __restrict__ col,
    const float* __restrict__ dinv, const float* __restrict__ bias,
    bf16_t* __restrict__ out, int N) {
  int wave = threadIdx.x >> 6;
  int lane = threadIdx.x & 63;
  int node = blockIdx.x * 4 + wave;
  if (node >= N) return;
  float di = dinv[node];
  unsigned su = ((const unsigned*)(t + (size_t)node * CDIM))[lane];
  float ax = bflo(su) * di;   // self term: will be scaled by di at the end
  float ay = bfhi(su) * di;
  int beg = rowptr[node], end = rowptr[node + 1];
  for (int base = beg; base < end; base += 64) {
    int rem = end - base;
    int cnt = rem < 64 ? rem : 64;
    int sL = 0; float wL = 0.f;
    if (lane < cnt) { sL = col[base + lane]; wL = dinv[sL]; }
    int k = 0;
    for (; k + 3 < cnt; k += 4) {
      int s0 = __shfl(sL, k, 64),     s1 = __shfl(sL, k + 1, 64);
      int s2 = __shfl(sL, k + 2, 64), s3 = __shfl(sL, k + 3, 64);
      float w0 = __shfl(wL, k, 64),     w1 = __shfl(wL, k + 1, 64);
      float w2 = __shfl(wL, k + 2, 64), w3 = __shfl(wL, k + 3, 64);
      unsigned u0 = ((const unsigned*)(t + (size_t)s0 * CDIM))[lane];
      unsigned u1 = ((const unsigned*)(t + (size_t)s1 * CDIM))[lane];
      unsigned u2 = ((const unsigned*)(t + (size_t)s2 * CDIM))[lane];
      unsigned u3 = ((const unsigned*)(t + (size_t)s3 * CDIM))[lane];
      ax = fmaf(bflo(u0), w0, ax); ay = fmaf(bfhi(u0), w0, ay);
      ax = fmaf(bflo(u1), w1, ax); ay = fmaf(bfhi(u1), w1, ay);
      ax = fmaf(bflo(u2), w2, ax); ay = fmaf(bfhi(u2), w2, ay);
      ax = fmaf(bflo(u3), w3, ax); ay = fmaf(bfhi(u3), w3, ay);
    }
    for (; k < cnt; k++) {
      int s = __shfl(sL, k, 64);
      float w = __shfl(wL, k, 64);
      unsigned u = ((const unsigned*)(t + (size_t)s * CDIM))[lane];
      ax = fmaf(bflo(u), w, ax); ay = fmaf(bfhi(u), w, ay);
    }
  }
  float2 bb = ((const float2*)bias)[lane];
  float ox = fmaf(di, ax, bb.x);
  float oy = fmaf(di, ay, bb.y);
  ox = fmaxf(ox, 0.f); oy = fmaxf(oy, 0.f);
  unsigned o = ((unsigned)f2bf(oy) << 16) | f2bf(ox);
  ((unsigned*)(out + (size_t)node * CDIM))[lane] = o;
}

// ---------- global mean pool (batch is sorted), bf16 in, fp32 out ----------
__global__ __launch_bounds__(128) void k_pool(const bf16_t* __restrict__ h,
    const int* __restrict__ batch, float* __restrict__ g, int N) {
  int b = blockIdx.x;
  int lo = 0, hi = N;
  while (lo < hi) { int mid = (lo + hi) >> 1; if (batch[mid] < b) lo = mid + 1; else hi = mid; }
  int s = lo;
  lo = 0; hi = N;
  int key = b + 1;
  while (lo < hi) { int mid = (lo + hi) >> 1; if (batch[mid] < key) lo = mid + 1; else hi = mid; }
  int e = lo;
  int c = threadIdx.x;
  float acc = 0.f;
  for (int i = s; i < e; i++) acc += bf2f(h[(size_t)i * CDIM + c]);
  g[b * CDIM + c] = acc / fmaxf((float)(e - s), 1.f);
}

// ---------- MLP head ----------
__global__ __launch_bounds__(512) void k_mlp1(const float* __restrict__ g,
    const float* __restrict__ W, const float* __restrict__ b, float* __restrict__ o) {
  __shared__ float gs[CDIM];
  int bi = blockIdx.x, tid = threadIdx.x;
  if (tid < CDIM) gs[tid] = g[bi * CDIM + tid];
  __syncthreads();
  if (tid < 500) {
    float acc = b[tid];
#pragma unroll 4
    for (int k = 0; k < CDIM; k++) acc = fmaf(gs[k], W[k * 500 + tid], acc);
    o[bi * 500 + tid] = fmaxf(acc, 0.f);
  }
}

__global__ __launch_bounds__(128) void k_mlp2(const float* __restrict__ a,
    const float* __restrict__ W, const float* __restrict__ b, float* __restrict__ o) {
  __shared__ float as[500];
  int bi = blockIdx.x, tid = threadIdx.x;
  for (int k = tid; k < 500; k += 128) as[k] = a[bi * 500 + k];
  __syncthreads();
  if (tid < 100) {
    float acc = b[tid];
    for (int k = 0; k < 500; k++) acc = fmaf(as[k], W[k * 100 + tid], acc);
    o[bi * 100 + tid] = fmaxf(acc, 0.f);
  }
}

__global__ __launch_bounds__(64) void k_mlp3(const float* __restrict__ a,
    const float* __restrict__ w, const float* __restrict__ b, float* __restrict__ o) {
  int bi = blockIdx.x, lane = threadIdx.x;
  float v = a[bi * 100 + lane] * w[lane];
  if (lane + 64 < 100) v = fmaf(a[bi * 100 + lane + 64], w[lane + 64], v);
#pragma unroll
  for (int ofs = 32; ofs > 0; ofs >>= 1) v += __shfl_down(v, ofs, 64);
  if (lane == 0) o[bi] = v + b[0];
}

static inline size_t align_up(size_t v) { return (v + 255) & ~(size_t)255; }

extern "C" void kernel_launch(void* const* d_in, const int* in_sizes, int n_in,
                              void* d_out, int out_size, void* d_ws, size_t ws_size,
                              hipStream_t stream) {
  const float* x   = (const float*)d_in[0];
  const int*   ei  = (const int*)d_in[1];
  const int*   bat = (const int*)d_in[2];
  const float* W1  = (const float*)d_in[3];
  const float* b1  = (const float*)d_in[4];
  const float* W2  = (const float*)d_in[5];
  const float* b2  = (const float*)d_in[6];
  const float* Wm1 = (const float*)d_in[7];
  const float* bm1 = (const float*)d_in[8];
  const float* Wm2 = (const float*)d_in[9];
  const float* bm2 = (const float*)d_in[10];
  const float* Wm3 = (const float*)d_in[11];
  const float* bm3 = (const float*)d_in[12];
  float* out = (float*)d_out;

  const int E = in_sizes[1] / 2;
  const int N = in_sizes[2];
  const int* src = ei;
  const int* dst = ei + E;
  const int G = (N + 4095) / 4096;

  char* p = (char*)d_ws;
  bf16_t* t   = (bf16_t*)p; p += align_up((size_t)N * CDIM * 2);
  bf16_t* h   = (bf16_t*)p; p += align_up((size_t)N * CDIM * 2);
  int* counts = (int*)p;   p += align_up((size_t)N * 4);
  int* rowptr = (int*)p;   p += align_up((size_t)(N + 1) * 4);
  int* cursor = (int*)p;   p += align_up((size_t)N * 4);
  int* colx   = (int*)p;   p += align_up((size_t)E * 4);
  float* dinv = (float*)p; p += align_up((size_t)N * 4);
  int* bsums  = (int*)p;   p += align_up((size_t)G * 4);
  int* boffs  = (int*)p;   p += align_up((size_t)(G + 1) * 4);
  float* gb   = (float*)p; p += align_up((size_t)NGRAPH * CDIM * 4);
  float* m1   = (float*)p; p += align_up((size_t)NGRAPH * 500 * 4);
  float* m2   = (float*)p; p += align_up((size_t)NGRAPH * 100 * 4);
  (void)ws_size; (void)n_in; (void)out_size;

  hipMemsetAsync(counts, 0, (size_t)N * 4, stream);
  k_hist<<<(E + 255) / 256, 256, 0, stream>>>(dst, counts, E);
  k_bsum<<<G, 1024, 0, stream>>>(counts, bsums, N);
  k_boff<<<1, 1024, 0, stream>>>(bsums, boffs, G);
  k_scan2<<<G, 1024, 0, stream>>>(counts, boffs, rowptr, cursor, dinv, N);
  k_fill<<<(E + 255) / 256, 256, 0, stream>>>(src, dst, cursor, colx, E);

  k_gemm<0><<<(N + 127) / 128, 256, 0, stream>>>(x, W1, t, N);
  k_agg<<<(N + 3) / 4, 256, 0, stream>>>(t, rowptr, colx, dinv, b1, h, N);
  k_gemm<1><<<(N + 127) / 128, 256, 0, stream>>>(h, W2, t, N);
  k_agg<<<(N + 3) / 4, 256, 0, stream>>>(t, rowptr, colx, dinv, b2, h, N);

  k_pool<<<NGRAPH, 128, 0, stream>>>(h, bat, gb, N);
  k_mlp1<<<NGRAPH, 512, 0, stream>>>(gb, Wm1, bm1, m1);
  k_mlp2<<<NGRAPH, 128, 0, stream>>>(m1, Wm2, bm2, m2);
  k_mlp3<<<NGRAPH, 64, 0, stream>>>(m2, Wm3, bm3, out);
}